// Round 3
// baseline (353.731 us; speedup 1.0000x reference)
//
#include <hip/hip_runtime.h>
#include <hip/hip_bf16.h>

typedef __hip_bfloat16 bf16;
typedef __attribute__((ext_vector_type(8))) short short8;
typedef __attribute__((ext_vector_type(4))) float f32x4;
typedef __attribute__((ext_vector_type(2))) float f32x2;

#define HID 64
#define CAP 4096            // slots per 128-node bucket (mean fill ~2048)
#define BSH 7               // bucket = node >> 7 (128 nodes / bucket)
#define EPB 4096            // edges per bin_kernel block (391 blocks @ E=1.6M)
#define SMAX 2048           // staged CSR indices per agg block (avg need ~64)

__device__ __forceinline__ float bfbits2f(unsigned short b){
    union { unsigned u; float f; } c; c.u = ((unsigned)b) << 16; return c.f;
}
// f32 -> bf16 bits, round-to-nearest-even
__device__ __forceinline__ unsigned short f2bfbits(float x){
    union { float f; unsigned u; } c; c.f = x;
    unsigned r = c.u + 0x7fffu + ((c.u >> 16) & 1u);
    return (unsigned short)(r >> 16);
}
// fp8 e4m3 (OCP) encode/decode via gfx950 HW converts
__device__ __forceinline__ unsigned char f2fp8(float x){
    unsigned v = __builtin_amdgcn_cvt_pk_fp8_f32(x, x, 0u, false);
    return (unsigned char)(v & 0xffu);
}
template<bool HI>
__device__ __forceinline__ f32x2 cvtpk(unsigned u){
    return __builtin_amdgcn_cvt_pk_f32_fp8(u, HI);   // 2 fp8 -> 2 f32, one instr
}

// ---------------- pass 1: bin edges by destination bucket ----------------
// LDS-staged: histogram -> 1024-scan -> rank-scatter into LDS -> LINEAR write-out.
// binned writes become bucket-run-contiguous (full 64B lines) instead of 4B scatter.

__global__ __launch_bounds__(256) void bin_kernel(const int* __restrict__ row,
                                                  const int* __restrict__ col,
                                                  int E, int NB,
                                                  int* __restrict__ gCur,
                                                  int* __restrict__ binned){
    __shared__ int lCnt[1024];
    __shared__ int lOff[1024];          // local exclusive start per bucket
    __shared__ int lGB[1024];           // b*CAP + globalBase - lOff[b]
    __shared__ int sPay[EPB];
    __shared__ unsigned short sB[EPB];
    __shared__ int sc[256];
    int tid = threadIdx.x;
    int e0 = blockIdx.x * EPB;
    int eN = E - e0; if (eN > EPB) eN = EPB;

    for (int b = tid; b < 1024; b += 256) lCnt[b] = 0;
    __syncthreads();
    for (int i = tid; i < eN; i += 256)
        atomicAdd(&lCnt[col[e0 + i] >> BSH], 1);
    __syncthreads();

    // exclusive scan of lCnt[0..1023]: 4 buckets/thread + 256-wide log scan
    int base = tid * 4;
    int c0 = lCnt[base], c1 = lCnt[base + 1], c2 = lCnt[base + 2], c3 = lCnt[base + 3];
    int s01 = c0 + c1, sAll = s01 + c2 + c3;
    sc[tid] = sAll;
    __syncthreads();
    for (int off = 1; off < 256; off <<= 1){
        int t = (tid >= off) ? sc[tid - off] : 0;
        __syncthreads();
        sc[tid] += t;
        __syncthreads();
    }
    int ex = sc[tid] - sAll;            // exclusive prefix of this thread's group
    lOff[base]     = ex;
    lOff[base + 1] = ex + c0;
    lOff[base + 2] = ex + s01;
    lOff[base + 3] = ex + s01 + c2;
    // global reservation per non-empty bucket
    #pragma unroll
    for (int k = 0; k < 4; ++k){
        int b = base + k;
        int c = lCnt[b];
        if (c){
            int gb = atomicAdd(&gCur[b], c);
            lGB[b] = b * CAP + gb - lOff[b];
        }
    }
    lCnt[base] = 0; lCnt[base + 1] = 0; lCnt[base + 2] = 0; lCnt[base + 3] = 0;
    __syncthreads();

    // rank-scatter into LDS (bucket-sorted positions)
    for (int i = tid; i < eN; i += 256){
        int e = e0 + i;
        int c = col[e];
        int bk = c >> BSH;
        int rk = atomicAdd(&lCnt[bk], 1);
        int pos = lOff[bk] + rk;
        sPay[pos] = ((c & 127) << 17) | row[e];
        sB[pos] = (unsigned short)bk;
    }
    __syncthreads();

    // linear write-out: contiguous within each bucket run
    for (int i = tid; i < eN; i += 256){
        int bk = sB[i];
        int tgt = lGB[bk] + i;
        int within = tgt - (bk << 12);          // CAP = 4096
        if (within < CAP) binned[tgt] = sPay[i];
    }
}

// ---------------- pass 2: per-bucket CSR build (LDS-staged, coalesced I/O) ----------------

__global__ __launch_bounds__(256) void build_kernel(const int* __restrict__ gCur,
                                                    const int* __restrict__ binned,
                                                    int* __restrict__ csr_row,
                                                    int* __restrict__ col_ptr,
                                                    int* __restrict__ col_end,
                                                    float* __restrict__ dinv, int N){
    __shared__ int sBin[CAP];
    __shared__ int sCsr[CAP];
    __shared__ int fineCnt[128];
    __shared__ int sc[128];
    __shared__ int fineCur[128];
    int b = blockIdx.x, tid = threadIdx.x;
    int j0 = b * CAP;
    int cnt = gCur[b];
    if (cnt > CAP) cnt = CAP;
    for (int i = tid; i < cnt; i += 256) sBin[i] = binned[j0 + i];
    if (tid < 128) fineCnt[tid] = 0;
    __syncthreads();
    for (int i = tid; i < cnt; i += 256)
        atomicAdd(&fineCnt[sBin[i] >> 17], 1);
    __syncthreads();
    if (tid < 128) sc[tid] = fineCnt[tid];
    __syncthreads();
    for (int off = 1; off < 128; off <<= 1){
        int t = 0;
        if (tid < 128 && tid >= off) t = sc[tid - off];
        __syncthreads();
        if (tid < 128) sc[tid] += t;
        __syncthreads();
    }
    if (tid < 128){
        int cf = fineCnt[tid];
        int startL = sc[tid] - cf;            // local exclusive prefix
        fineCur[tid] = startL;
        int node = (b << BSH) + tid;
        if (node < N){
            col_ptr[node] = j0 + startL;
            col_end[node] = j0 + startL + cf;
            dinv[node] = rsqrtf((float)cf + 1.0f);
        }
    }
    __syncthreads();
    for (int i = tid; i < cnt; i += 256){
        int w = sBin[i];
        int pos = atomicAdd(&fineCur[w >> 17], 1);
        sCsr[pos] = w & 0x1FFFF;
    }
    __syncthreads();
    for (int i = tid; i < cnt; i += 256) csr_row[j0 + i] = sCsr[i];
}

// ---------------- MFMA matmul: H[N,64](fp8) = dinv[n] * (act[N,K] @ W[K,64]) ----------------

template<int K, typename T>
__global__ __launch_bounds__(256) void matmul_kernel(const T* __restrict__ act,
                                                     const float* __restrict__ W,
                                                     const float* __restrict__ dinv,
                                                     unsigned char* __restrict__ H8, int N){
    constexpr int KS = K / 32;
    constexpr int RB = 2 * K;
    __shared__ __align__(16) short As[128 * K];
    __shared__ __align__(16) short Wt[64 * K];

    int tid = threadIdx.x;
    int nodeBase = blockIdx.x * 128;

    for (int i = tid; i < K * 64; i += 256){
        int k = i >> 6, c = i & 63;
        unsigned short b = f2bfbits(W[i]);
        int byte = c * RB + ((2 * k) ^ ((c & 7) << 4));
        *(short*)((char*)Wt + byte) = (short)b;
    }
    constexpr int OPR = K / 8;
    for (int i = tid; i < 128 * OPR; i += 256){
        int node = i / OPR, oct = i % OPR;
        int n = nodeBase + node;
        short8 v = (short8)0;
        if (n < N){
            if constexpr (sizeof(T) == 4){
                const float4* xp = (const float4*)&act[(size_t)n * K + oct * 8];
                float4 a = xp[0], b = xp[1];
                v[0] = (short)f2bfbits(a.x); v[1] = (short)f2bfbits(a.y);
                v[2] = (short)f2bfbits(a.z); v[3] = (short)f2bfbits(a.w);
                v[4] = (short)f2bfbits(b.x); v[5] = (short)f2bfbits(b.y);
                v[6] = (short)f2bfbits(b.z); v[7] = (short)f2bfbits(b.w);
            } else {
                v = *(const short8*)&act[(size_t)n * K + oct * 8];
            }
        }
        int byte = node * RB + ((oct * 16) ^ ((node & 7) << 4));
        *(short8*)((char*)As + byte) = v;
    }
    __syncthreads();

    int wv = tid >> 6, l = tid & 63;
    int lr = l & 15, lg = l >> 4;

    short8 bfr[KS][4];
    #pragma unroll
    for (int ks = 0; ks < KS; ++ks)
        #pragma unroll
        for (int t = 0; t < 4; ++t){
            int c = t * 16 + lr;
            int byte = c * RB + ((ks * 64 + lg * 16) ^ ((c & 7) << 4));
            bfr[ks][t] = *(const short8*)((const char*)Wt + byte);
        }

    #pragma unroll
    for (int nt = 0; nt < 2; ++nt){
        int nb = wv * 32 + nt * 16;
        int node = nb + lr;
        short8 af[KS];
        #pragma unroll
        for (int ks = 0; ks < KS; ++ks){
            int byte = node * RB + ((ks * 64 + lg * 16) ^ ((node & 7) << 4));
            af[ks] = *(const short8*)((const char*)As + byte);
        }
        f32x4 acc[4] = {(f32x4)0.f, (f32x4)0.f, (f32x4)0.f, (f32x4)0.f};
        #pragma unroll
        for (int ks = 0; ks < KS; ++ks)
            #pragma unroll
            for (int t = 0; t < 4; ++t)
                acc[t] = __builtin_amdgcn_mfma_f32_16x16x32_bf16(af[ks], bfr[ks][t], acc[t], 0, 0, 0);
        #pragma unroll
        for (int r = 0; r < 4; ++r){
            int n = nodeBase + nb + lg * 4 + r;
            if (n < N){
                float dv = dinv[n];
                #pragma unroll
                for (int t = 0; t < 4; ++t)
                    H8[((size_t)(unsigned)n << 6) + t * 16 + lr] = f2fp8(acc[t][r] * dv);
            }
        }
    }
}

// ---------------- fused aggregate + bias + LayerNorm + ReLU (+optional pool) ----------------
// Lane mapping: lane = (g = l>>4, s = l&15). Group g gathers edges ≡ g (mod 4),
// loading a DWORD (features 4s..4s+3) -> 4 edges per VMEM instruction, decoded
// with v_cvt_pk_f32_fp8. Groups merged by shfl_xor(16,32) butterfly (bitwise-
// deterministic: only commutativity reorder). LN over 64 feats = 16-lane butterfly.

template<bool POOL>
__global__ __launch_bounds__(256) void agg_ln_kernel(const unsigned char* __restrict__ H8,
                                                     const float* __restrict__ dinv,
                                                     const int* __restrict__ col_ptr,
                                                     const int* __restrict__ col_end,
                                                     const int* __restrict__ csr_row,
                                                     const float* __restrict__ bias,
                                                     const float* __restrict__ lnw,
                                                     const float* __restrict__ lnb,
                                                     bf16* __restrict__ out,
                                                     float* __restrict__ pooledRep, int N){
    __shared__ int sIdx[SMAX];
    __shared__ float sp[4][64];
    int tid = threadIdx.x;
    int wid = tid >> 6, l = tid & 63;
    int g = l >> 4, s = l & 15;
    int nodeBase = blockIdx.x * 4;
    int n = nodeBase + wid;
    bool valid = (n < N);
    int nc = valid ? n : nodeBase;

    int lastN = nodeBase + 3; if (lastN > N - 1) lastN = N - 1;
    int jlo = col_ptr[nodeBase];
    int jhi = col_end[lastN];
    int cnt = jhi - jlo;

    int j0 = col_ptr[nc];
    int j1 = valid ? col_end[nc] : j0;
    int deg = j1 - j0;

    bool fast = (cnt <= SMAX);
    if (fast){
        for (int i = tid; i < cnt; i += 256) sIdx[i] = csr_row[jlo + i];
    }
    __syncthreads();

    const char* Hs = (const char*)H8 + (s << 2);
    f32x2 aA = {0.f, 0.f}, aB = {0.f, 0.f}, bA = {0.f, 0.f}, bB = {0.f, 0.f};
    int full = deg >> 2, rem = deg & 3;

#define LOADU(r) (*(const unsigned*)(Hs + ((size_t)(unsigned)(r) << 6)))
#define GBODY(IDX) { \
        int i = 0; \
        for (; i + 2 <= full; i += 2){ \
            int e0 = (i << 2) + g; \
            int r0 = IDX(e0), r1 = IDX(e0 + 4); \
            unsigned u0 = LOADU(r0), u1 = LOADU(r1); \
            aA += cvtpk<false>(u0); aB += cvtpk<true>(u0); \
            bA += cvtpk<false>(u1); bB += cvtpk<true>(u1); \
        } \
        if (i < full){ \
            int r0 = IDX((i << 2) + g); \
            unsigned u0 = LOADU(r0); \
            aA += cvtpk<false>(u0); aB += cvtpk<true>(u0); \
        } \
        if (rem){ \
            bool on = g < rem; \
            int ec = (full << 2) + (on ? g : 0); \
            int r0 = IDX(ec); \
            unsigned u0 = LOADU(r0); \
            f32x2 z0 = cvtpk<false>(u0), z1 = cvtpk<true>(u0); \
            if (on){ bA += z0; bB += z1; } \
        } }

    if (fast){
        int p = j0 - jlo;
#define IDXF(e) sIdx[p + (e)]
        GBODY(IDXF)
#undef IDXF
    } else {
#define IDXS(e) csr_row[j0 + (e)]
        GBODY(IDXS)
#undef IDXS
    }

    f32x2 A2 = aA + bA, B2 = aB + bB;
    // merge the 4 edge-groups
    A2.x += __shfl_xor(A2.x, 16); A2.y += __shfl_xor(A2.y, 16);
    B2.x += __shfl_xor(B2.x, 16); B2.y += __shfl_xor(B2.y, 16);
    A2.x += __shfl_xor(A2.x, 32); A2.y += __shfl_xor(A2.y, 32);
    B2.x += __shfl_xor(B2.x, 32); B2.y += __shfl_xor(B2.y, 32);
    // self-loop
    unsigned us = LOADU(nc);
    A2 += cvtpk<false>(us); B2 += cvtpk<true>(us);

    float dv = dinv[nc];
    float4 b4 = ((const float4*)bias)[s];
    float a0 = fmaf(dv, A2.x, b4.x);
    float a1 = fmaf(dv, A2.y, b4.y);
    float a2 = fmaf(dv, B2.x, b4.z);
    float a3 = fmaf(dv, B2.y, b4.w);

    float sum = (a0 + a1) + (a2 + a3);
    #pragma unroll
    for (int m = 1; m < 16; m <<= 1) sum += __shfl_xor(sum, m);
    float mu = sum * (1.0f / 64.0f);
    float d0 = a0 - mu, d1 = a1 - mu, d2 = a2 - mu, d3 = a3 - mu;
    float v = (d0 * d0 + d1 * d1) + (d2 * d2 + d3 * d3);
    #pragma unroll
    for (int m = 1; m < 16; m <<= 1) v += __shfl_xor(v, m);
    float rstd = rsqrtf(v * (1.0f / 64.0f) + 1e-5f);
    float4 w4 = ((const float4*)lnw)[s];
    float4 c4 = ((const float4*)lnb)[s];
    float y0 = fmaxf(fmaf(d0 * rstd, w4.x, c4.x), 0.0f);
    float y1 = fmaxf(fmaf(d1 * rstd, w4.y, c4.y), 0.0f);
    float y2 = fmaxf(fmaf(d2 * rstd, w4.z, c4.z), 0.0f);
    float y3 = fmaxf(fmaf(d3 * rstd, w4.w, c4.w), 0.0f);

    if (POOL){
        if (g == 0){
            float4 yv = valid ? make_float4(y0, y1, y2, y3)
                              : make_float4(0.f, 0.f, 0.f, 0.f);
            ((float4*)sp[wid])[s] = yv;
        }
        __syncthreads();
        if (tid < 64){
            float t = sp[0][tid] + sp[1][tid] + sp[2][tid] + sp[3][tid];
            atomicAdd(&pooledRep[(blockIdx.x & 63) * 64 + tid], t);
        }
    } else {
        if (valid && g == 0){
            ushort4 o;
            o.x = f2bfbits(y0); o.y = f2bfbits(y1);
            o.z = f2bfbits(y2); o.w = f2bfbits(y3);
            ((ushort4*)out)[((size_t)(unsigned)nc << 4) + s] = o;
        }
    }
#undef LOADU
#undef GBODY
}

// ---------------- head: reduce 64 replicas + linear ----------------

__global__ __launch_bounds__(64) void final_kernel(const float* __restrict__ pooledRep,
                                                   const float* __restrict__ Wl,
                                                   const float* __restrict__ bl,
                                                   float* __restrict__ outp, float invN){
    __shared__ float pooled[64];
    int t = threadIdx.x;
    float s = 0.f;
    #pragma unroll 8
    for (int r = 0; r < 64; ++r) s += pooledRep[r * 64 + t];
    pooled[t] = s;
    __syncthreads();
    if (t < 25){
        float acc = bl[t];
        #pragma unroll 8
        for (int f = 0; f < HID; ++f)
            acc = fmaf(pooled[f] * invN, Wl[f * 25 + t], acc);
        outp[t] = acc;
    }
}

// ---------------- launch ----------------

static inline size_t alignup(size_t x){ return (x + 255) & ~(size_t)255; }

extern "C" void kernel_launch(void* const* d_in, const int* in_sizes, int n_in,
                              void* d_out, int out_size, void* d_ws, size_t ws_size,
                              hipStream_t stream) {
    const float* x   = (const float*)d_in[0];
    const int*   ei  = (const int*)d_in[1];
    const float* W1  = (const float*)d_in[2];
    const float* b1  = (const float*)d_in[3];
    const float* W2  = (const float*)d_in[4];
    const float* b2  = (const float*)d_in[5];
    const float* W3  = (const float*)d_in[6];
    const float* b3  = (const float*)d_in[7];
    const float* ln1w = (const float*)d_in[8];
    const float* ln1b = (const float*)d_in[9];
    const float* ln2w = (const float*)d_in[10];
    const float* ln2b = (const float*)d_in[11];
    const float* ln3w = (const float*)d_in[12];
    const float* ln3b = (const float*)d_in[13];
    const float* Wl  = (const float*)d_in[14];
    const float* bl  = (const float*)d_in[15];

    const int N = in_sizes[0] / 128;
    const int E = in_sizes[1] / 2;
    const int NB = (N + 127) >> BSH;
    const int* row = ei;
    const int* col = ei + E;

    char* p = (char*)d_ws;
    int*   gCur      = (int*)p;   p += alignup((size_t)NB * 4);
    float* pooledRep = (float*)p; p += alignup(64 * 64 * 4);
    size_t zeroBytes = (size_t)((char*)p - (char*)gCur);
    int*   binned    = (int*)p;   p += alignup((size_t)NB * CAP * 4);
    int*   csr_row   = (int*)p;   p += alignup((size_t)NB * CAP * 4);
    int*   col_ptr   = (int*)p;   p += alignup((size_t)N * 4);
    int*   col_end   = (int*)p;   p += alignup((size_t)N * 4);
    float* dinv      = (float*)p; p += alignup((size_t)N * 4);
    unsigned char* H8 = (unsigned char*)p; p += alignup((size_t)N * HID);
    bf16*  A         = (bf16*)p;  p += alignup((size_t)N * HID * 2);

    hipMemsetAsync(gCur, 0, zeroBytes, stream);

    int gB = (E + EPB - 1) / EPB;
    int gM = (N + 127) / 128;
    int gA = (N + 3) / 4;

    bin_kernel<<<gB, 256, 0, stream>>>(row, col, E, NB, gCur, binned);
    build_kernel<<<NB, 256, 0, stream>>>(gCur, binned, csr_row, col_ptr, col_end, dinv, N);

    // layer 1
    matmul_kernel<128, float><<<gM, 256, 0, stream>>>(x, W1, dinv, H8, N);
    agg_ln_kernel<false><<<gA, 256, 0, stream>>>(H8, dinv, col_ptr, col_end, csr_row,
                                                 b1, ln1w, ln1b, A, pooledRep, N);
    // layer 2
    matmul_kernel<64, bf16><<<gM, 256, 0, stream>>>(A, W2, dinv, H8, N);
    agg_ln_kernel<false><<<gA, 256, 0, stream>>>(H8, dinv, col_ptr, col_end, csr_row,
                                                 b2, ln2w, ln2b, A, pooledRep, N);
    // layer 3 (+fused mean-pool accumulate; A not written)
    matmul_kernel<64, bf16><<<gM, 256, 0, stream>>>(A, W3, dinv, H8, N);
    agg_ln_kernel<true><<<gA, 256, 0, stream>>>(H8, dinv, col_ptr, col_end, csr_row,
                                                b3, ln3w, ln3b, A, pooledRep, N);

    final_kernel<<<1, 64, 0, stream>>>(pooledRep, Wl, bl, (float*)d_out, 1.0f / (float)N);
}

// Round 4
// 322.127 us; speedup vs baseline: 1.0981x; 1.0981x over previous
//
#include <hip/hip_runtime.h>
#include <hip/hip_bf16.h>

typedef __hip_bfloat16 bf16;
typedef __attribute__((ext_vector_type(8))) short short8;
typedef __attribute__((ext_vector_type(4))) float f32x4;
typedef __attribute__((ext_vector_type(2))) float f32x2;

#define HID 64
#define CAP 4096            // slots per 128-node bucket (mean fill ~2048)
#define BSH 7               // bucket = node >> 7 (128 nodes / bucket)
#define EPB 4096            // edges per bin_kernel block (391 blocks @ E=1.6M)
#define SMAX 2048           // staged CSR indices per agg block (avg need ~64)

__device__ __forceinline__ float bfbits2f(unsigned short b){
    union { unsigned u; float f; } c; c.u = ((unsigned)b) << 16; return c.f;
}
// f32 -> bf16 bits, round-to-nearest-even
__device__ __forceinline__ unsigned short f2bfbits(float x){
    union { float f; unsigned u; } c; c.f = x;
    unsigned r = c.u + 0x7fffu + ((c.u >> 16) & 1u);
    return (unsigned short)(r >> 16);
}
// fp8 e4m3 (OCP) encode/decode via gfx950 HW converts
__device__ __forceinline__ unsigned char f2fp8(float x){
    unsigned v = __builtin_amdgcn_cvt_pk_fp8_f32(x, x, 0u, false);
    return (unsigned char)(v & 0xffu);
}
template<bool HI>
__device__ __forceinline__ f32x2 cvtpk(unsigned u){
    return __builtin_amdgcn_cvt_pk_f32_fp8(u, HI);   // 2 fp8 -> 2 f32, one instr
}

// ---------------- pass 1: bin edges by destination bucket ----------------
// LDS-staged sort-by-bucket with LINEAR global write-out (full-line writes).
// v4: 1024 threads/block (occupancy fix — r3 ran at 13% with 256 thr),
// one bucket per thread, hierarchical shfl scan (2 barriers, no 16-step log scan),
// edges preloaded to registers (col read once).

__global__ __launch_bounds__(1024) void bin_kernel(const int* __restrict__ row,
                                                   const int* __restrict__ col,
                                                   int E, int NB,
                                                   int* __restrict__ gCur,
                                                   int* __restrict__ binned){
    __shared__ int lCnt[1024];
    __shared__ int lOff[1024];          // local exclusive start per bucket
    __shared__ int lGB[1024];           // b*CAP + globalBase - lOff[b]
    __shared__ int sPay[EPB];
    __shared__ unsigned short sB[EPB];
    __shared__ int wSum[16];
    int tid = threadIdx.x;
    int lane = tid & 63, wv = tid >> 6;
    int e0 = blockIdx.x * EPB;
    int eN = E - e0; if (eN > EPB) eN = EPB;

    lCnt[tid] = 0;
    // preload this thread's 4 edges (coalesced; col read once for both phases)
    int cols[4], rows[4];
    #pragma unroll
    for (int k = 0; k < 4; ++k){
        int i = tid + k * 1024;
        bool ok = (i < eN);
        cols[k] = ok ? col[e0 + i] : -1;
        rows[k] = ok ? row[e0 + i] : 0;
    }
    __syncthreads();
    #pragma unroll
    for (int k = 0; k < 4; ++k)
        if (cols[k] >= 0) atomicAdd(&lCnt[cols[k] >> BSH], 1);
    __syncthreads();

    // hierarchical exclusive scan over 1024 buckets (1 bucket/thread)
    int c = lCnt[tid];
    int inc = c;
    #pragma unroll
    for (int m = 1; m < 64; m <<= 1){
        int t = __shfl_up(inc, m);
        if (lane >= m) inc += t;
    }
    if (lane == 63) wSum[wv] = inc;
    __syncthreads();
    if (wv == 0 && lane < 16){
        int orig = wSum[lane];
        int ws = orig;
        #pragma unroll
        for (int m = 1; m < 16; m <<= 1){
            int t = __shfl_up(ws, m);
            if (lane >= m) ws += t;
        }
        wSum[lane] = ws - orig;         // exclusive wave offset
    }
    __syncthreads();
    int excl = inc - c + wSum[wv];      // exclusive prefix for bucket=tid
    lOff[tid] = excl;
    if (c){
        int gb = atomicAdd(&gCur[tid], c);
        lGB[tid] = tid * CAP + gb - excl;
    }
    lCnt[tid] = 0;
    __syncthreads();

    // rank-scatter into LDS (bucket-sorted positions)
    #pragma unroll
    for (int k = 0; k < 4; ++k){
        if (cols[k] >= 0){
            int bk = cols[k] >> BSH;
            int rk = atomicAdd(&lCnt[bk], 1);
            int pos = lOff[bk] + rk;
            sPay[pos] = ((cols[k] & 127) << 17) | rows[k];
            sB[pos] = (unsigned short)bk;
        }
    }
    __syncthreads();

    // linear write-out: contiguous within each bucket run
    #pragma unroll
    for (int k = 0; k < 4; ++k){
        int i = tid + k * 1024;
        if (i < eN){
            int bk = sB[i];
            int tgt = lGB[bk] + i;
            if (tgt - (bk << 12) < CAP)           // CAP = 4096; overflow guard
                binned[tgt] = sPay[i];
        }
    }
}

// ---------------- pass 2: per-bucket CSR build (LDS-staged, 512 threads) ----------------

__global__ __launch_bounds__(512) void build_kernel(const int* __restrict__ gCur,
                                                    const int* __restrict__ binned,
                                                    int* __restrict__ csr_row,
                                                    int* __restrict__ col_ptr,
                                                    int* __restrict__ col_end,
                                                    float* __restrict__ dinv, int N){
    __shared__ int sBin[CAP];
    __shared__ int sCsr[CAP];
    __shared__ int fineCnt[128];
    __shared__ int sc[128];
    __shared__ int fineCur[128];
    int b = blockIdx.x, tid = threadIdx.x;
    int j0 = b * CAP;
    int cnt = gCur[b];
    if (cnt > CAP) cnt = CAP;
    for (int i = tid; i < cnt; i += 512) sBin[i] = binned[j0 + i];
    if (tid < 128) fineCnt[tid] = 0;
    __syncthreads();
    for (int i = tid; i < cnt; i += 512)
        atomicAdd(&fineCnt[sBin[i] >> 17], 1);
    __syncthreads();
    // scan over 128 node-counters: 2 wave-scans + combine
    if (tid < 128){
        int lane = tid & 63, w = tid >> 6;
        int cf = fineCnt[tid];
        int inc = cf;
        #pragma unroll
        for (int m = 1; m < 64; m <<= 1){
            int t = __shfl_up(inc, m);
            if (lane >= m) inc += t;
        }
        if (lane == 63) sc[w] = inc;
        __syncthreads();
        int waveOff = (w == 1) ? sc[0] : 0;
        int startL = waveOff + inc - cf;      // local exclusive prefix
        fineCur[tid] = startL;
        int node = (b << BSH) + tid;
        if (node < N){
            col_ptr[node] = j0 + startL;
            col_end[node] = j0 + startL + cf;
            dinv[node] = rsqrtf((float)cf + 1.0f);
        }
    } else {
        __syncthreads();
    }
    __syncthreads();
    for (int i = tid; i < cnt; i += 512){
        int w = sBin[i];
        int pos = atomicAdd(&fineCur[w >> 17], 1);
        sCsr[pos] = w & 0x1FFFF;
    }
    __syncthreads();
    for (int i = tid; i < cnt; i += 512) csr_row[j0 + i] = sCsr[i];
}

// ---------------- MFMA matmul: H[N,64](fp8) = dinv[n] * (act[N,K] @ W[K,64]) ----------------

template<int K, typename T>
__global__ __launch_bounds__(256) void matmul_kernel(const T* __restrict__ act,
                                                     const float* __restrict__ W,
                                                     const float* __restrict__ dinv,
                                                     unsigned char* __restrict__ H8, int N){
    constexpr int KS = K / 32;
    constexpr int RB = 2 * K;
    __shared__ __align__(16) short As[128 * K];
    __shared__ __align__(16) short Wt[64 * K];

    int tid = threadIdx.x;
    int nodeBase = blockIdx.x * 128;

    for (int i = tid; i < K * 64; i += 256){
        int k = i >> 6, c = i & 63;
        unsigned short b = f2bfbits(W[i]);
        int byte = c * RB + ((2 * k) ^ ((c & 7) << 4));
        *(short*)((char*)Wt + byte) = (short)b;
    }
    constexpr int OPR = K / 8;
    for (int i = tid; i < 128 * OPR; i += 256){
        int node = i / OPR, oct = i % OPR;
        int n = nodeBase + node;
        short8 v = (short8)0;
        if (n < N){
            if constexpr (sizeof(T) == 4){
                const float4* xp = (const float4*)&act[(size_t)n * K + oct * 8];
                float4 a = xp[0], b = xp[1];
                v[0] = (short)f2bfbits(a.x); v[1] = (short)f2bfbits(a.y);
                v[2] = (short)f2bfbits(a.z); v[3] = (short)f2bfbits(a.w);
                v[4] = (short)f2bfbits(b.x); v[5] = (short)f2bfbits(b.y);
                v[6] = (short)f2bfbits(b.z); v[7] = (short)f2bfbits(b.w);
            } else {
                v = *(const short8*)&act[(size_t)n * K + oct * 8];
            }
        }
        int byte = node * RB + ((oct * 16) ^ ((node & 7) << 4));
        *(short8*)((char*)As + byte) = v;
    }
    __syncthreads();

    int wv = tid >> 6, l = tid & 63;
    int lr = l & 15, lg = l >> 4;

    short8 bfr[KS][4];
    #pragma unroll
    for (int ks = 0; ks < KS; ++ks)
        #pragma unroll
        for (int t = 0; t < 4; ++t){
            int c = t * 16 + lr;
            int byte = c * RB + ((ks * 64 + lg * 16) ^ ((c & 7) << 4));
            bfr[ks][t] = *(const short8*)((const char*)Wt + byte);
        }

    #pragma unroll
    for (int nt = 0; nt < 2; ++nt){
        int nb = wv * 32 + nt * 16;
        int node = nb + lr;
        short8 af[KS];
        #pragma unroll
        for (int ks = 0; ks < KS; ++ks){
            int byte = node * RB + ((ks * 64 + lg * 16) ^ ((node & 7) << 4));
            af[ks] = *(const short8*)((const char*)As + byte);
        }
        f32x4 acc[4] = {(f32x4)0.f, (f32x4)0.f, (f32x4)0.f, (f32x4)0.f};
        #pragma unroll
        for (int ks = 0; ks < KS; ++ks)
            #pragma unroll
            for (int t = 0; t < 4; ++t)
                acc[t] = __builtin_amdgcn_mfma_f32_16x16x32_bf16(af[ks], bfr[ks][t], acc[t], 0, 0, 0);
        #pragma unroll
        for (int r = 0; r < 4; ++r){
            int n = nodeBase + nb + lg * 4 + r;
            if (n < N){
                float dv = dinv[n];
                #pragma unroll
                for (int t = 0; t < 4; ++t)
                    H8[((size_t)(unsigned)n << 6) + t * 16 + lr] = f2fp8(acc[t][r] * dv);
            }
        }
    }
}

// ---------------- fused aggregate + bias + LayerNorm + ReLU (+optional pool) ----------------
// Lane = (g = l>>4, s = l&15); group g gathers edges ≡ g (mod 4) via DWORD loads
// (4 edges per VMEM instr), v_cvt_pk_f32_fp8 decode, shfl_xor(16,32) group merge.

template<bool POOL>
__global__ __launch_bounds__(256) void agg_ln_kernel(const unsigned char* __restrict__ H8,
                                                     const float* __restrict__ dinv,
                                                     const int* __restrict__ col_ptr,
                                                     const int* __restrict__ col_end,
                                                     const int* __restrict__ csr_row,
                                                     const float* __restrict__ bias,
                                                     const float* __restrict__ lnw,
                                                     const float* __restrict__ lnb,
                                                     bf16* __restrict__ out,
                                                     float* __restrict__ pooledRep, int N){
    __shared__ int sIdx[SMAX];
    __shared__ float sp[4][64];
    int tid = threadIdx.x;
    int wid = tid >> 6, l = tid & 63;
    int g = l >> 4, s = l & 15;
    int nodeBase = blockIdx.x * 4;
    int n = nodeBase + wid;
    bool valid = (n < N);
    int nc = valid ? n : nodeBase;

    int lastN = nodeBase + 3; if (lastN > N - 1) lastN = N - 1;
    int jlo = col_ptr[nodeBase];
    int jhi = col_end[lastN];
    int cnt = jhi - jlo;

    int j0 = col_ptr[nc];
    int j1 = valid ? col_end[nc] : j0;
    int deg = j1 - j0;

    bool fast = (cnt <= SMAX);
    if (fast){
        for (int i = tid; i < cnt; i += 256) sIdx[i] = csr_row[jlo + i];
    }
    __syncthreads();

    const char* Hs = (const char*)H8 + (s << 2);
    f32x2 aA = {0.f, 0.f}, aB = {0.f, 0.f}, bA = {0.f, 0.f}, bB = {0.f, 0.f};
    int full = deg >> 2, rem = deg & 3;

#define LOADU(r) (*(const unsigned*)(Hs + ((size_t)(unsigned)(r) << 6)))
#define GBODY(IDX) { \
        int i = 0; \
        for (; i + 2 <= full; i += 2){ \
            int e0 = (i << 2) + g; \
            int r0 = IDX(e0), r1 = IDX(e0 + 4); \
            unsigned u0 = LOADU(r0), u1 = LOADU(r1); \
            aA += cvtpk<false>(u0); aB += cvtpk<true>(u0); \
            bA += cvtpk<false>(u1); bB += cvtpk<true>(u1); \
        } \
        if (i < full){ \
            int r0 = IDX((i << 2) + g); \
            unsigned u0 = LOADU(r0); \
            aA += cvtpk<false>(u0); aB += cvtpk<true>(u0); \
        } \
        if (rem){ \
            bool on = g < rem; \
            int ec = (full << 2) + (on ? g : 0); \
            int r0 = IDX(ec); \
            unsigned u0 = LOADU(r0); \
            f32x2 z0 = cvtpk<false>(u0), z1 = cvtpk<true>(u0); \
            if (on){ bA += z0; bB += z1; } \
        } }

    if (fast){
        int p = j0 - jlo;
#define IDXF(e) sIdx[p + (e)]
        GBODY(IDXF)
#undef IDXF
    } else {
#define IDXS(e) csr_row[j0 + (e)]
        GBODY(IDXS)
#undef IDXS
    }

    f32x2 A2 = aA + bA, B2 = aB + bB;
    A2.x += __shfl_xor(A2.x, 16); A2.y += __shfl_xor(A2.y, 16);
    B2.x += __shfl_xor(B2.x, 16); B2.y += __shfl_xor(B2.y, 16);
    A2.x += __shfl_xor(A2.x, 32); A2.y += __shfl_xor(A2.y, 32);
    B2.x += __shfl_xor(B2.x, 32); B2.y += __shfl_xor(B2.y, 32);
    unsigned us = LOADU(nc);
    A2 += cvtpk<false>(us); B2 += cvtpk<true>(us);

    float dv = dinv[nc];
    float4 b4 = ((const float4*)bias)[s];
    float a0 = fmaf(dv, A2.x, b4.x);
    float a1 = fmaf(dv, A2.y, b4.y);
    float a2 = fmaf(dv, B2.x, b4.z);
    float a3 = fmaf(dv, B2.y, b4.w);

    float sum = (a0 + a1) + (a2 + a3);
    #pragma unroll
    for (int m = 1; m < 16; m <<= 1) sum += __shfl_xor(sum, m);
    float mu = sum * (1.0f / 64.0f);
    float d0 = a0 - mu, d1 = a1 - mu, d2 = a2 - mu, d3 = a3 - mu;
    float v = (d0 * d0 + d1 * d1) + (d2 * d2 + d3 * d3);
    #pragma unroll
    for (int m = 1; m < 16; m <<= 1) v += __shfl_xor(v, m);
    float rstd = rsqrtf(v * (1.0f / 64.0f) + 1e-5f);
    float4 w4 = ((const float4*)lnw)[s];
    float4 c4 = ((const float4*)lnb)[s];
    float y0 = fmaxf(fmaf(d0 * rstd, w4.x, c4.x), 0.0f);
    float y1 = fmaxf(fmaf(d1 * rstd, w4.y, c4.y), 0.0f);
    float y2 = fmaxf(fmaf(d2 * rstd, w4.z, c4.z), 0.0f);
    float y3 = fmaxf(fmaf(d3 * rstd, w4.w, c4.w), 0.0f);

    if (POOL){
        if (g == 0){
            float4 yv = valid ? make_float4(y0, y1, y2, y3)
                              : make_float4(0.f, 0.f, 0.f, 0.f);
            ((float4*)sp[wid])[s] = yv;
        }
        __syncthreads();
        if (tid < 64){
            float t = sp[0][tid] + sp[1][tid] + sp[2][tid] + sp[3][tid];
            atomicAdd(&pooledRep[(blockIdx.x & 63) * 64 + tid], t);
        }
    } else {
        if (valid && g == 0){
            ushort4 o;
            o.x = f2bfbits(y0); o.y = f2bfbits(y1);
            o.z = f2bfbits(y2); o.w = f2bfbits(y3);
            ((ushort4*)out)[((size_t)(unsigned)nc << 4) + s] = o;
        }
    }
#undef LOADU
#undef GBODY
}

// ---------------- head: reduce 64 replicas + linear ----------------

__global__ __launch_bounds__(64) void final_kernel(const float* __restrict__ pooledRep,
                                                   const float* __restrict__ Wl,
                                                   const float* __restrict__ bl,
                                                   float* __restrict__ outp, float invN){
    __shared__ float pooled[64];
    int t = threadIdx.x;
    float s = 0.f;
    #pragma unroll 8
    for (int r = 0; r < 64; ++r) s += pooledRep[r * 64 + t];
    pooled[t] = s;
    __syncthreads();
    if (t < 25){
        float acc = bl[t];
        #pragma unroll 8
        for (int f = 0; f < HID; ++f)
            acc = fmaf(pooled[f] * invN, Wl[f * 25 + t], acc);
        outp[t] = acc;
    }
}

// ---------------- launch ----------------

static inline size_t alignup(size_t x){ return (x + 255) & ~(size_t)255; }

extern "C" void kernel_launch(void* const* d_in, const int* in_sizes, int n_in,
                              void* d_out, int out_size, void* d_ws, size_t ws_size,
                              hipStream_t stream) {
    const float* x   = (const float*)d_in[0];
    const int*   ei  = (const int*)d_in[1];
    const float* W1  = (const float*)d_in[2];
    const float* b1  = (const float*)d_in[3];
    const float* W2  = (const float*)d_in[4];
    const float* b2  = (const float*)d_in[5];
    const float* W3  = (const float*)d_in[6];
    const float* b3  = (const float*)d_in[7];
    const float* ln1w = (const float*)d_in[8];
    const float* ln1b = (const float*)d_in[9];
    const float* ln2w = (const float*)d_in[10];
    const float* ln2b = (const float*)d_in[11];
    const float* ln3w = (const float*)d_in[12];
    const float* ln3b = (const float*)d_in[13];
    const float* Wl  = (const float*)d_in[14];
    const float* bl  = (const float*)d_in[15];

    const int N = in_sizes[0] / 128;
    const int E = in_sizes[1] / 2;
    const int NB = (N + 127) >> BSH;
    const int* row = ei;
    const int* col = ei + E;

    char* p = (char*)d_ws;
    int*   gCur      = (int*)p;   p += alignup((size_t)NB * 4);
    float* pooledRep = (float*)p; p += alignup(64 * 64 * 4);
    size_t zeroBytes = (size_t)((char*)p - (char*)gCur);
    int*   binned    = (int*)p;   p += alignup((size_t)NB * CAP * 4);
    int*   csr_row   = (int*)p;   p += alignup((size_t)NB * CAP * 4);
    int*   col_ptr   = (int*)p;   p += alignup((size_t)N * 4);
    int*   col_end   = (int*)p;   p += alignup((size_t)N * 4);
    float* dinv      = (float*)p; p += alignup((size_t)N * 4);
    unsigned char* H8 = (unsigned char*)p; p += alignup((size_t)N * HID);
    bf16*  A         = (bf16*)p;  p += alignup((size_t)N * HID * 2);

    hipMemsetAsync(gCur, 0, zeroBytes, stream);

    int gB = (E + EPB - 1) / EPB;
    int gM = (N + 127) / 128;
    int gA = (N + 3) / 4;

    bin_kernel<<<gB, 1024, 0, stream>>>(row, col, E, NB, gCur, binned);
    build_kernel<<<NB, 512, 0, stream>>>(gCur, binned, csr_row, col_ptr, col_end, dinv, N);

    // layer 1
    matmul_kernel<128, float><<<gM, 256, 0, stream>>>(x, W1, dinv, H8, N);
    agg_ln_kernel<false><<<gA, 256, 0, stream>>>(H8, dinv, col_ptr, col_end, csr_row,
                                                 b1, ln1w, ln1b, A, pooledRep, N);
    // layer 2
    matmul_kernel<64, bf16><<<gM, 256, 0, stream>>>(A, W2, dinv, H8, N);
    agg_ln_kernel<false><<<gA, 256, 0, stream>>>(H8, dinv, col_ptr, col_end, csr_row,
                                                 b2, ln2w, ln2b, A, pooledRep, N);
    // layer 3 (+fused mean-pool accumulate; A not written)
    matmul_kernel<64, bf16><<<gM, 256, 0, stream>>>(A, W3, dinv, H8, N);
    agg_ln_kernel<true><<<gA, 256, 0, stream>>>(H8, dinv, col_ptr, col_end, csr_row,
                                                b3, ln3w, ln3b, A, pooledRep, N);

    final_kernel<<<1, 64, 0, stream>>>(pooledRep, Wl, bl, (float*)d_out, 1.0f / (float)N);
}

// Round 5
// 245.816 us; speedup vs baseline: 1.4390x; 1.3104x over previous
//
#include <hip/hip_runtime.h>
#include <hip/hip_bf16.h>

typedef __hip_bfloat16 bf16;
typedef __attribute__((ext_vector_type(8))) short short8;
typedef __attribute__((ext_vector_type(4))) float f32x4;
typedef __attribute__((ext_vector_type(2))) float f32x2;

#define HID 64
#define CAP 4096            // slots per 128-node bucket (mean fill ~2048)
#define BSH 7               // bucket = node >> 7 (128 nodes / bucket)
#define EPB 4096            // edges per bin_kernel block (391 blocks @ E=1.6M)
#define SMAX 2048           // staged CSR indices per agg block (32 nodes, avg need ~512)

__device__ __forceinline__ float bfbits2f(unsigned short b){
    union { unsigned u; float f; } c; c.u = ((unsigned)b) << 16; return c.f;
}
// f32 -> bf16 bits, round-to-nearest-even
__device__ __forceinline__ unsigned short f2bfbits(float x){
    union { float f; unsigned u; } c; c.f = x;
    unsigned r = c.u + 0x7fffu + ((c.u >> 16) & 1u);
    return (unsigned short)(r >> 16);
}
// fp8 e4m3 (OCP) encode/decode via gfx950 HW converts
__device__ __forceinline__ unsigned char f2fp8(float x){
    unsigned v = __builtin_amdgcn_cvt_pk_fp8_f32(x, x, 0u, false);
    return (unsigned char)(v & 0xffu);
}
template<bool HI>
__device__ __forceinline__ f32x2 cvtpk(unsigned u){
    return __builtin_amdgcn_cvt_pk_f32_fp8(u, HI);   // 2 fp8 -> 2 f32, one instr
}

// ---------------- pass 1: bin edges by destination bucket ----------------
// LDS-staged sort-by-bucket with LINEAR global write-out (full-line writes).
// 1024 threads/block, one bucket per thread, hierarchical shfl scan.

__global__ __launch_bounds__(1024) void bin_kernel(const int* __restrict__ row,
                                                   const int* __restrict__ col,
                                                   int E, int NB,
                                                   int* __restrict__ gCur,
                                                   int* __restrict__ binned){
    __shared__ int lCnt[1024];
    __shared__ int lOff[1024];          // local exclusive start per bucket
    __shared__ int lGB[1024];           // b*CAP + globalBase - lOff[b]
    __shared__ int sPay[EPB];
    __shared__ unsigned short sB[EPB];
    __shared__ int wSum[16];
    int tid = threadIdx.x;
    int lane = tid & 63, wv = tid >> 6;
    int e0 = blockIdx.x * EPB;
    int eN = E - e0; if (eN > EPB) eN = EPB;

    lCnt[tid] = 0;
    int cols[4], rows[4];
    #pragma unroll
    for (int k = 0; k < 4; ++k){
        int i = tid + k * 1024;
        bool ok = (i < eN);
        cols[k] = ok ? col[e0 + i] : -1;
        rows[k] = ok ? row[e0 + i] : 0;
    }
    __syncthreads();
    #pragma unroll
    for (int k = 0; k < 4; ++k)
        if (cols[k] >= 0) atomicAdd(&lCnt[cols[k] >> BSH], 1);
    __syncthreads();

    int c = lCnt[tid];
    int inc = c;
    #pragma unroll
    for (int m = 1; m < 64; m <<= 1){
        int t = __shfl_up(inc, m);
        if (lane >= m) inc += t;
    }
    if (lane == 63) wSum[wv] = inc;
    __syncthreads();
    if (wv == 0 && lane < 16){
        int orig = wSum[lane];
        int ws = orig;
        #pragma unroll
        for (int m = 1; m < 16; m <<= 1){
            int t = __shfl_up(ws, m);
            if (lane >= m) ws += t;
        }
        wSum[lane] = ws - orig;
    }
    __syncthreads();
    int excl = inc - c + wSum[wv];
    lOff[tid] = excl;
    if (c){
        int gb = atomicAdd(&gCur[tid], c);
        lGB[tid] = tid * CAP + gb - excl;
    }
    lCnt[tid] = 0;
    __syncthreads();

    #pragma unroll
    for (int k = 0; k < 4; ++k){
        if (cols[k] >= 0){
            int bk = cols[k] >> BSH;
            int rk = atomicAdd(&lCnt[bk], 1);
            int pos = lOff[bk] + rk;
            sPay[pos] = ((cols[k] & 127) << 17) | rows[k];
            sB[pos] = (unsigned short)bk;
        }
    }
    __syncthreads();

    #pragma unroll
    for (int k = 0; k < 4; ++k){
        int i = tid + k * 1024;
        if (i < eN){
            int bk = sB[i];
            int tgt = lGB[bk] + i;
            if (tgt - (bk << 12) < CAP)
                binned[tgt] = sPay[i];
        }
    }
}

// ---------------- pass 2: per-bucket CSR build (LDS-staged, 512 threads) ----------------

__global__ __launch_bounds__(512) void build_kernel(const int* __restrict__ gCur,
                                                    const int* __restrict__ binned,
                                                    int* __restrict__ csr_row,
                                                    int* __restrict__ col_ptr,
                                                    int* __restrict__ col_end,
                                                    float* __restrict__ dinv, int N){
    __shared__ int sBin[CAP];
    __shared__ int sCsr[CAP];
    __shared__ int fineCnt[128];
    __shared__ int sc[128];
    __shared__ int fineCur[128];
    int b = blockIdx.x, tid = threadIdx.x;
    int j0 = b * CAP;
    int cnt = gCur[b];
    if (cnt > CAP) cnt = CAP;
    for (int i = tid; i < cnt; i += 512) sBin[i] = binned[j0 + i];
    if (tid < 128) fineCnt[tid] = 0;
    __syncthreads();
    for (int i = tid; i < cnt; i += 512)
        atomicAdd(&fineCnt[sBin[i] >> 17], 1);
    __syncthreads();
    if (tid < 128){
        int lane = tid & 63, w = tid >> 6;
        int cf = fineCnt[tid];
        int inc = cf;
        #pragma unroll
        for (int m = 1; m < 64; m <<= 1){
            int t = __shfl_up(inc, m);
            if (lane >= m) inc += t;
        }
        if (lane == 63) sc[w] = inc;
        __syncthreads();
        int waveOff = (w == 1) ? sc[0] : 0;
        int startL = waveOff + inc - cf;
        fineCur[tid] = startL;
        int node = (b << BSH) + tid;
        if (node < N){
            col_ptr[node] = j0 + startL;
            col_end[node] = j0 + startL + cf;
            dinv[node] = rsqrtf((float)cf + 1.0f);
        }
    } else {
        __syncthreads();
    }
    __syncthreads();
    for (int i = tid; i < cnt; i += 512){
        int w = sBin[i];
        int pos = atomicAdd(&fineCur[w >> 17], 1);
        sCsr[pos] = w & 0x1FFFF;
    }
    __syncthreads();
    for (int i = tid; i < cnt; i += 512) csr_row[j0 + i] = sCsr[i];
}

// ---------------- MFMA matmul: H[N,64](fp8) = dinv[n] * (act[N,K] @ W[K,64]) ----------------

template<int K, typename T>
__global__ __launch_bounds__(256) void matmul_kernel(const T* __restrict__ act,
                                                     const float* __restrict__ W,
                                                     const float* __restrict__ dinv,
                                                     unsigned char* __restrict__ H8, int N){
    constexpr int KS = K / 32;
    constexpr int RB = 2 * K;
    __shared__ __align__(16) short As[128 * K];
    __shared__ __align__(16) short Wt[64 * K];

    int tid = threadIdx.x;
    int nodeBase = blockIdx.x * 128;

    for (int i = tid; i < K * 64; i += 256){
        int k = i >> 6, c = i & 63;
        unsigned short b = f2bfbits(W[i]);
        int byte = c * RB + ((2 * k) ^ ((c & 7) << 4));
        *(short*)((char*)Wt + byte) = (short)b;
    }
    constexpr int OPR = K / 8;
    for (int i = tid; i < 128 * OPR; i += 256){
        int node = i / OPR, oct = i % OPR;
        int n = nodeBase + node;
        short8 v = (short8)0;
        if (n < N){
            if constexpr (sizeof(T) == 4){
                const float4* xp = (const float4*)&act[(size_t)n * K + oct * 8];
                float4 a = xp[0], b = xp[1];
                v[0] = (short)f2bfbits(a.x); v[1] = (short)f2bfbits(a.y);
                v[2] = (short)f2bfbits(a.z); v[3] = (short)f2bfbits(a.w);
                v[4] = (short)f2bfbits(b.x); v[5] = (short)f2bfbits(b.y);
                v[6] = (short)f2bfbits(b.z); v[7] = (short)f2bfbits(b.w);
            } else {
                v = *(const short8*)&act[(size_t)n * K + oct * 8];
            }
        }
        int byte = node * RB + ((oct * 16) ^ ((node & 7) << 4));
        *(short8*)((char*)As + byte) = v;
    }
    __syncthreads();

    int wv = tid >> 6, l = tid & 63;
    int lr = l & 15, lg = l >> 4;

    short8 bfr[KS][4];
    #pragma unroll
    for (int ks = 0; ks < KS; ++ks)
        #pragma unroll
        for (int t = 0; t < 4; ++t){
            int c = t * 16 + lr;
            int byte = c * RB + ((ks * 64 + lg * 16) ^ ((c & 7) << 4));
            bfr[ks][t] = *(const short8*)((const char*)Wt + byte);
        }

    #pragma unroll
    for (int nt = 0; nt < 2; ++nt){
        int nb = wv * 32 + nt * 16;
        int node = nb + lr;
        short8 af[KS];
        #pragma unroll
        for (int ks = 0; ks < KS; ++ks){
            int byte = node * RB + ((ks * 64 + lg * 16) ^ ((node & 7) << 4));
            af[ks] = *(const short8*)((const char*)As + byte);
        }
        f32x4 acc[4] = {(f32x4)0.f, (f32x4)0.f, (f32x4)0.f, (f32x4)0.f};
        #pragma unroll
        for (int ks = 0; ks < KS; ++ks)
            #pragma unroll
            for (int t = 0; t < 4; ++t)
                acc[t] = __builtin_amdgcn_mfma_f32_16x16x32_bf16(af[ks], bfr[ks][t], acc[t], 0, 0, 0);
        #pragma unroll
        for (int r = 0; r < 4; ++r){
            int n = nodeBase + nb + lg * 4 + r;
            if (n < N){
                float dv = dinv[n];
                #pragma unroll
                for (int t = 0; t < 4; ++t)
                    H8[((size_t)(unsigned)n << 6) + t * 16 + lr] = f2fp8(acc[t][r] * dv);
            }
        }
    }
}

// ---------------- fused aggregate + bias + LayerNorm + ReLU (+optional pool) ----------------
// v5: 8 nodes PER WAVE (lane = g=node(l>>3), s=feature-octet(l&7)); dwordx2 gathers
// (8 lanes cover one 64B row). Wave count drops 8x -> fixed overhead (prologue/LN/
// epilogue) amortized. Loop runs wave-max degree; inactive edges read the ZEROED
// row N of H8 (branch-free accumulate, +0.0 exact). sIdx padded 2x so speculative
// in-LDS reads past a group's range are safe (values discarded by index select).

template<bool POOL>
__global__ __launch_bounds__(256) void agg_ln_kernel(const unsigned char* __restrict__ H8,
                                                     const float* __restrict__ dinv,
                                                     const int* __restrict__ col_ptr,
                                                     const int* __restrict__ col_end,
                                                     const int* __restrict__ csr_row,
                                                     const float* __restrict__ bias,
                                                     const float* __restrict__ lnw,
                                                     const float* __restrict__ lnb,
                                                     bf16* __restrict__ out,
                                                     float* __restrict__ pooledRep, int N){
    __shared__ int sIdx[2 * SMAX];
    __shared__ float sp[4][64];
    int tid = threadIdx.x;
    int wid = tid >> 6, l = tid & 63;
    int g = l >> 3, s = l & 7;            // node sub-idx (0..7), feature octet (0..7)
    int nodeBase = blockIdx.x * 32;
    int n = nodeBase + wid * 8 + g;
    bool valid = (n < N);
    int nc = valid ? n : nodeBase;

    int lastN = nodeBase + 31; if (lastN > N - 1) lastN = N - 1;
    int jlo = col_ptr[nodeBase];
    int jhi = col_end[lastN];
    int cnt = jhi - jlo;

    int j0 = col_ptr[nc];
    int j1 = valid ? col_end[nc] : j0;
    int deg = j1 - j0;

    bool fast = (cnt <= SMAX);
    if (fast){
        for (int i = tid; i < cnt; i += 256) sIdx[i] = csr_row[jlo + i];
    }
    __syncthreads();

    unsigned soff = (unsigned)(s << 3);   // byte offset of this lane's octet
    const char* Hb = (const char*)H8;
    // self-loop (issued early, overlaps)
    uint2 us = *(const uint2*)(Hb + ((((unsigned)nc) << 6) | soff));

    // wave-max degree (deg uniform within each 8-lane group)
    int mdeg = deg;
    mdeg = max(mdeg, __shfl_xor(mdeg, 8));
    mdeg = max(mdeg, __shfl_xor(mdeg, 16));
    mdeg = max(mdeg, __shfl_xor(mdeg, 32));

    f32x2 a0 = {0.f,0.f}, a1 = {0.f,0.f}, a2 = {0.f,0.f}, a3 = {0.f,0.f};

#define ACC(u)  { a0 += cvtpk<false>((u).x); a1 += cvtpk<true>((u).x); \
                  a2 += cvtpk<false>((u).y); a3 += cvtpk<true>((u).y); }
#define GLOOP(IDX) \
    for (int i = 0; i < mdeg; i += 4){ \
        int r0 = (i     < deg) ? IDX(i    ) : N; \
        int r1 = (i + 1 < deg) ? IDX(i + 1) : N; \
        int r2 = (i + 2 < deg) ? IDX(i + 2) : N; \
        int r3 = (i + 3 < deg) ? IDX(i + 3) : N; \
        uint2 u0 = *(const uint2*)(Hb + ((((unsigned)r0) << 6) | soff)); \
        uint2 u1 = *(const uint2*)(Hb + ((((unsigned)r1) << 6) | soff)); \
        uint2 u2 = *(const uint2*)(Hb + ((((unsigned)r2) << 6) | soff)); \
        uint2 u3 = *(const uint2*)(Hb + ((((unsigned)r3) << 6) | soff)); \
        ACC(u0) ACC(u1) ACC(u2) ACC(u3) \
    }

    if (fast){
        int p = j0 - jlo;
#define IDXF(e) sIdx[p + (e)]
        GLOOP(IDXF)
#undef IDXF
    } else {
#define IDXS(e) csr_row[j0 + (e)]
        GLOOP(IDXS)
#undef IDXS
    }
#undef GLOOP
#undef ACC

    // self-loop term
    a0 += cvtpk<false>(us.x); a1 += cvtpk<true>(us.x);
    a2 += cvtpk<false>(us.y); a3 += cvtpk<true>(us.y);

    float dv = dinv[nc];
    float4 b4a = ((const float4*)bias)[2 * s];
    float4 b4b = ((const float4*)bias)[2 * s + 1];
    float v0 = fmaf(dv, a0.x, b4a.x), v1 = fmaf(dv, a0.y, b4a.y);
    float v2 = fmaf(dv, a1.x, b4a.z), v3 = fmaf(dv, a1.y, b4a.w);
    float v4 = fmaf(dv, a2.x, b4b.x), v5 = fmaf(dv, a2.y, b4b.y);
    float v6 = fmaf(dv, a3.x, b4b.z), v7 = fmaf(dv, a3.y, b4b.w);

    // LayerNorm over 64 features: per-lane sum of 8 + 3-step butterfly over group
    float sum = ((v0 + v1) + (v2 + v3)) + ((v4 + v5) + (v6 + v7));
    #pragma unroll
    for (int m = 1; m < 8; m <<= 1) sum += __shfl_xor(sum, m);
    float mu = sum * (1.0f / 64.0f);
    float d0 = v0 - mu, d1 = v1 - mu, d2 = v2 - mu, d3 = v3 - mu;
    float d4 = v4 - mu, d5 = v5 - mu, d6 = v6 - mu, d7 = v7 - mu;
    float var = ((d0*d0 + d1*d1) + (d2*d2 + d3*d3)) + ((d4*d4 + d5*d5) + (d6*d6 + d7*d7));
    #pragma unroll
    for (int m = 1; m < 8; m <<= 1) var += __shfl_xor(var, m);
    float rstd = rsqrtf(var * (1.0f / 64.0f) + 1e-5f);
    float4 w4a = ((const float4*)lnw)[2 * s];
    float4 w4b = ((const float4*)lnw)[2 * s + 1];
    float4 c4a = ((const float4*)lnb)[2 * s];
    float4 c4b = ((const float4*)lnb)[2 * s + 1];
    float y0 = fmaxf(fmaf(d0 * rstd, w4a.x, c4a.x), 0.0f);
    float y1 = fmaxf(fmaf(d1 * rstd, w4a.y, c4a.y), 0.0f);
    float y2 = fmaxf(fmaf(d2 * rstd, w4a.z, c4a.z), 0.0f);
    float y3 = fmaxf(fmaf(d3 * rstd, w4a.w, c4a.w), 0.0f);
    float y4 = fmaxf(fmaf(d4 * rstd, w4b.x, c4b.x), 0.0f);
    float y5 = fmaxf(fmaf(d5 * rstd, w4b.y, c4b.y), 0.0f);
    float y6 = fmaxf(fmaf(d6 * rstd, w4b.z, c4b.z), 0.0f);
    float y7 = fmaxf(fmaf(d7 * rstd, w4b.w, c4b.w), 0.0f);

    if (POOL){
        float z0 = valid ? y0 : 0.f, z1 = valid ? y1 : 0.f;
        float z2 = valid ? y2 : 0.f, z3 = valid ? y3 : 0.f;
        float z4 = valid ? y4 : 0.f, z5 = valid ? y5 : 0.f;
        float z6 = valid ? y6 : 0.f, z7 = valid ? y7 : 0.f;
        // reduce across the 8 node-groups (flip g bits)
        #pragma unroll
        for (int m = 8; m < 64; m <<= 1){
            z0 += __shfl_xor(z0, m); z1 += __shfl_xor(z1, m);
            z2 += __shfl_xor(z2, m); z3 += __shfl_xor(z3, m);
            z4 += __shfl_xor(z4, m); z5 += __shfl_xor(z5, m);
            z6 += __shfl_xor(z6, m); z7 += __shfl_xor(z7, m);
        }
        if (g == 0){
            ((float4*)sp[wid])[2 * s]     = make_float4(z0, z1, z2, z3);
            ((float4*)sp[wid])[2 * s + 1] = make_float4(z4, z5, z6, z7);
        }
        __syncthreads();
        if (tid < 64){
            float t = sp[0][tid] + sp[1][tid] + sp[2][tid] + sp[3][tid];
            atomicAdd(&pooledRep[(blockIdx.x & 63) * 64 + tid], t);
        }
    } else {
        if (valid){
            short8 o;
            o[0] = (short)f2bfbits(y0); o[1] = (short)f2bfbits(y1);
            o[2] = (short)f2bfbits(y2); o[3] = (short)f2bfbits(y3);
            o[4] = (short)f2bfbits(y4); o[5] = (short)f2bfbits(y5);
            o[6] = (short)f2bfbits(y6); o[7] = (short)f2bfbits(y7);
            *(short8*)((short*)out + (((size_t)(unsigned)nc) << 6) + (s << 3)) = o;
        }
    }
}

// ---------------- head: reduce 64 replicas + linear ----------------

__global__ __launch_bounds__(64) void final_kernel(const float* __restrict__ pooledRep,
                                                   const float* __restrict__ Wl,
                                                   const float* __restrict__ bl,
                                                   float* __restrict__ outp, float invN){
    __shared__ float pooled[64];
    int t = threadIdx.x;
    float s = 0.f;
    #pragma unroll 8
    for (int r = 0; r < 64; ++r) s += pooledRep[r * 64 + t];
    pooled[t] = s;
    __syncthreads();
    if (t < 25){
        float acc = bl[t];
        #pragma unroll 8
        for (int f = 0; f < HID; ++f)
            acc = fmaf(pooled[f] * invN, Wl[f * 25 + t], acc);
        outp[t] = acc;
    }
}

// ---------------- launch ----------------

static inline size_t alignup(size_t x){ return (x + 255) & ~(size_t)255; }

extern "C" void kernel_launch(void* const* d_in, const int* in_sizes, int n_in,
                              void* d_out, int out_size, void* d_ws, size_t ws_size,
                              hipStream_t stream) {
    const float* x   = (const float*)d_in[0];
    const int*   ei  = (const int*)d_in[1];
    const float* W1  = (const float*)d_in[2];
    const float* b1  = (const float*)d_in[3];
    const float* W2  = (const float*)d_in[4];
    const float* b2  = (const float*)d_in[5];
    const float* W3  = (const float*)d_in[6];
    const float* b3  = (const float*)d_in[7];
    const float* ln1w = (const float*)d_in[8];
    const float* ln1b = (const float*)d_in[9];
    const float* ln2w = (const float*)d_in[10];
    const float* ln2b = (const float*)d_in[11];
    const float* ln3w = (const float*)d_in[12];
    const float* ln3b = (const float*)d_in[13];
    const float* Wl  = (const float*)d_in[14];
    const float* bl  = (const float*)d_in[15];

    const int N = in_sizes[0] / 128;
    const int E = in_sizes[1] / 2;
    const int NB = (N + 127) >> BSH;
    const int* row = ei;
    const int* col = ei + E;

    char* p = (char*)d_ws;
    int*   gCur      = (int*)p;   p += alignup((size_t)NB * 4);
    float* pooledRep = (float*)p; p += alignup(64 * 64 * 4);
    size_t zeroBytes = (size_t)((char*)p - (char*)gCur);
    int*   binned    = (int*)p;   p += alignup((size_t)NB * CAP * 4);
    int*   csr_row   = (int*)p;   p += alignup((size_t)NB * CAP * 4);
    int*   col_ptr   = (int*)p;   p += alignup((size_t)N * 4);
    int*   col_end   = (int*)p;   p += alignup((size_t)N * 4);
    float* dinv      = (float*)p; p += alignup((size_t)N * 4);
    unsigned char* H8 = (unsigned char*)p; p += alignup(((size_t)N + 1) * HID);
    bf16*  A         = (bf16*)p;  p += alignup((size_t)N * HID * 2);

    hipMemsetAsync(gCur, 0, zeroBytes, stream);
    hipMemsetAsync(H8 + (size_t)N * HID, 0, HID, stream);   // zero row N (gather sink)

    int gB = (E + EPB - 1) / EPB;
    int gM = (N + 127) / 128;
    int gA = (N + 31) / 32;

    bin_kernel<<<gB, 1024, 0, stream>>>(row, col, E, NB, gCur, binned);
    build_kernel<<<NB, 512, 0, stream>>>(gCur, binned, csr_row, col_ptr, col_end, dinv, N);

    // layer 1
    matmul_kernel<128, float><<<gM, 256, 0, stream>>>(x, W1, dinv, H8, N);
    agg_ln_kernel<false><<<gA, 256, 0, stream>>>(H8, dinv, col_ptr, col_end, csr_row,
                                                 b1, ln1w, ln1b, A, pooledRep, N);
    // layer 2
    matmul_kernel<64, bf16><<<gM, 256, 0, stream>>>(A, W2, dinv, H8, N);
    agg_ln_kernel<false><<<gA, 256, 0, stream>>>(H8, dinv, col_ptr, col_end, csr_row,
                                                 b2, ln2w, ln2b, A, pooledRep, N);
    // layer 3 (+fused mean-pool accumulate; A not written)
    matmul_kernel<64, bf16><<<gM, 256, 0, stream>>>(A, W3, dinv, H8, N);
    agg_ln_kernel<true><<<gA, 256, 0, stream>>>(H8, dinv, col_ptr, col_end, csr_row,
                                                b3, ln3w, ln3b, A, pooledRep, N);

    final_kernel<<<1, 64, 0, stream>>>(pooledRep, Wl, bl, (float*)d_out, 1.0f / (float)N);
}

// Round 6
// 241.159 us; speedup vs baseline: 1.4668x; 1.0193x over previous
//
#include <hip/hip_runtime.h>
#include <hip/hip_bf16.h>

typedef __hip_bfloat16 bf16;
typedef __attribute__((ext_vector_type(8))) short short8;
typedef __attribute__((ext_vector_type(4))) float f32x4;
typedef __attribute__((ext_vector_type(2))) float f32x2;

#define HID 64
#define CAP 4096            // slots per 128-node bucket (mean fill ~2048)
#define BSH 7               // bucket = node >> 7 (128 nodes / bucket)
#define EPB 4096            // edges per bin_kernel block (391 blocks @ E=1.6M)
#define SMAX 2048           // staged CSR indices per agg block (64 nodes, avg need ~1024)

__device__ __forceinline__ float bfbits2f(unsigned short b){
    union { unsigned u; float f; } c; c.u = ((unsigned)b) << 16; return c.f;
}
// f32 -> bf16 bits, round-to-nearest-even
__device__ __forceinline__ unsigned short f2bfbits(float x){
    union { float f; unsigned u; } c; c.f = x;
    unsigned r = c.u + 0x7fffu + ((c.u >> 16) & 1u);
    return (unsigned short)(r >> 16);
}
// fp8 e4m3 (OCP) encode/decode via gfx950 HW converts
__device__ __forceinline__ unsigned char f2fp8(float x){
    unsigned v = __builtin_amdgcn_cvt_pk_fp8_f32(x, x, 0u, false);
    return (unsigned char)(v & 0xffu);
}
template<bool HI>
__device__ __forceinline__ f32x2 cvtpk(unsigned u){
    return __builtin_amdgcn_cvt_pk_f32_fp8(u, HI);   // 2 fp8 -> 2 f32, one instr
}

// ---------------- pass 1: bin edges by destination bucket ----------------
// LDS-staged sort-by-bucket with LINEAR global write-out (full-line writes).
// 1024 threads/block, one bucket per thread, hierarchical shfl scan.

__global__ __launch_bounds__(1024) void bin_kernel(const int* __restrict__ row,
                                                   const int* __restrict__ col,
                                                   int E, int NB,
                                                   int* __restrict__ gCur,
                                                   int* __restrict__ binned){
    __shared__ int lCnt[1024];
    __shared__ int lOff[1024];          // local exclusive start per bucket
    __shared__ int lGB[1024];           // b*CAP + globalBase - lOff[b]
    __shared__ int sPay[EPB];
    __shared__ unsigned short sB[EPB];
    __shared__ int wSum[16];
    int tid = threadIdx.x;
    int lane = tid & 63, wv = tid >> 6;
    int e0 = blockIdx.x * EPB;
    int eN = E - e0; if (eN > EPB) eN = EPB;

    lCnt[tid] = 0;
    int cols[4], rows[4];
    #pragma unroll
    for (int k = 0; k < 4; ++k){
        int i = tid + k * 1024;
        bool ok = (i < eN);
        cols[k] = ok ? col[e0 + i] : -1;
        rows[k] = ok ? row[e0 + i] : 0;
    }
    __syncthreads();
    #pragma unroll
    for (int k = 0; k < 4; ++k)
        if (cols[k] >= 0) atomicAdd(&lCnt[cols[k] >> BSH], 1);
    __syncthreads();

    int c = lCnt[tid];
    int inc = c;
    #pragma unroll
    for (int m = 1; m < 64; m <<= 1){
        int t = __shfl_up(inc, m);
        if (lane >= m) inc += t;
    }
    if (lane == 63) wSum[wv] = inc;
    __syncthreads();
    if (wv == 0 && lane < 16){
        int orig = wSum[lane];
        int ws = orig;
        #pragma unroll
        for (int m = 1; m < 16; m <<= 1){
            int t = __shfl_up(ws, m);
            if (lane >= m) ws += t;
        }
        wSum[lane] = ws - orig;
    }
    __syncthreads();
    int excl = inc - c + wSum[wv];
    lOff[tid] = excl;
    if (c){
        int gb = atomicAdd(&gCur[tid], c);
        lGB[tid] = tid * CAP + gb - excl;
    }
    lCnt[tid] = 0;
    __syncthreads();

    #pragma unroll
    for (int k = 0; k < 4; ++k){
        if (cols[k] >= 0){
            int bk = cols[k] >> BSH;
            int rk = atomicAdd(&lCnt[bk], 1);
            int pos = lOff[bk] + rk;
            sPay[pos] = ((cols[k] & 127) << 17) | rows[k];
            sB[pos] = (unsigned short)bk;
        }
    }
    __syncthreads();

    #pragma unroll
    for (int k = 0; k < 4; ++k){
        int i = tid + k * 1024;
        if (i < eN){
            int bk = sB[i];
            int tgt = lGB[bk] + i;
            if (tgt - (bk << 12) < CAP)
                binned[tgt] = sPay[i];
        }
    }
}

// ---------------- pass 2: per-bucket CSR build (LDS-staged, 512 threads) ----------------
// Also zeroes the gather-sink row N of both H8 buffers (block 0; saves a memset launch;
// must re-run every launch because the harness re-poisons the workspace).

__global__ __launch_bounds__(512) void build_kernel(const int* __restrict__ gCur,
                                                    const int* __restrict__ binned,
                                                    int* __restrict__ csr_row,
                                                    int* __restrict__ col_ptr,
                                                    int* __restrict__ col_end,
                                                    float* __restrict__ dinv,
                                                    unsigned char* __restrict__ H8a,
                                                    unsigned char* __restrict__ H8b, int N){
    __shared__ int sBin[CAP];
    __shared__ int sCsr[CAP];
    __shared__ int fineCnt[128];
    __shared__ int sc[128];
    __shared__ int fineCur[128];
    int b = blockIdx.x, tid = threadIdx.x;
    if (b == 0 && tid >= 480){
        int t = tid - 480;
        if (t < 16) ((unsigned*)(H8a + ((size_t)N << 6)))[t] = 0u;
        else        ((unsigned*)(H8b + ((size_t)N << 6)))[t - 16] = 0u;
    }
    int j0 = b * CAP;
    int cnt = gCur[b];
    if (cnt > CAP) cnt = CAP;
    for (int i = tid; i < cnt; i += 512) sBin[i] = binned[j0 + i];
    if (tid < 128) fineCnt[tid] = 0;
    __syncthreads();
    for (int i = tid; i < cnt; i += 512)
        atomicAdd(&fineCnt[sBin[i] >> 17], 1);
    __syncthreads();
    if (tid < 128){
        int lane = tid & 63, w = tid >> 6;
        int cf = fineCnt[tid];
        int inc = cf;
        #pragma unroll
        for (int m = 1; m < 64; m <<= 1){
            int t = __shfl_up(inc, m);
            if (lane >= m) inc += t;
        }
        if (lane == 63) sc[w] = inc;
        __syncthreads();
        int waveOff = (w == 1) ? sc[0] : 0;
        int startL = waveOff + inc - cf;
        fineCur[tid] = startL;
        int node = (b << BSH) + tid;
        if (node < N){
            col_ptr[node] = j0 + startL;
            col_end[node] = j0 + startL + cf;
            dinv[node] = rsqrtf((float)cf + 1.0f);
        }
    } else {
        __syncthreads();
    }
    __syncthreads();
    for (int i = tid; i < cnt; i += 512){
        int w = sBin[i];
        int pos = atomicAdd(&fineCur[w >> 17], 1);
        sCsr[pos] = w & 0x1FFFF;
    }
    __syncthreads();
    for (int i = tid; i < cnt; i += 512) csr_row[j0 + i] = sCsr[i];
}

// ---------------- MFMA matmul (layer 1 only): H[N,64](fp8) = dinv*(x[N,128]@W1) ----------------

template<int K, typename T>
__global__ __launch_bounds__(256) void matmul_kernel(const T* __restrict__ act,
                                                     const float* __restrict__ W,
                                                     const float* __restrict__ dinv,
                                                     unsigned char* __restrict__ H8, int N){
    constexpr int KS = K / 32;
    constexpr int RB = 2 * K;
    __shared__ __align__(16) short As[128 * K];
    __shared__ __align__(16) short Wt[64 * K];

    int tid = threadIdx.x;
    int nodeBase = blockIdx.x * 128;

    for (int i = tid; i < K * 64; i += 256){
        int k = i >> 6, c = i & 63;
        unsigned short b = f2bfbits(W[i]);
        int byte = c * RB + ((2 * k) ^ ((c & 7) << 4));
        *(short*)((char*)Wt + byte) = (short)b;
    }
    constexpr int OPR = K / 8;
    for (int i = tid; i < 128 * OPR; i += 256){
        int node = i / OPR, oct = i % OPR;
        int n = nodeBase + node;
        short8 v = (short8)0;
        if (n < N){
            if constexpr (sizeof(T) == 4){
                const float4* xp = (const float4*)&act[(size_t)n * K + oct * 8];
                float4 a = xp[0], b = xp[1];
                v[0] = (short)f2bfbits(a.x); v[1] = (short)f2bfbits(a.y);
                v[2] = (short)f2bfbits(a.z); v[3] = (short)f2bfbits(a.w);
                v[4] = (short)f2bfbits(b.x); v[5] = (short)f2bfbits(b.y);
                v[6] = (short)f2bfbits(b.z); v[7] = (short)f2bfbits(b.w);
            } else {
                v = *(const short8*)&act[(size_t)n * K + oct * 8];
            }
        }
        int byte = node * RB + ((oct * 16) ^ ((node & 7) << 4));
        *(short8*)((char*)As + byte) = v;
    }
    __syncthreads();

    int wv = tid >> 6, l = tid & 63;
    int lr = l & 15, lg = l >> 4;

    short8 bfr[KS][4];
    #pragma unroll
    for (int ks = 0; ks < KS; ++ks)
        #pragma unroll
        for (int t = 0; t < 4; ++t){
            int c = t * 16 + lr;
            int byte = c * RB + ((ks * 64 + lg * 16) ^ ((c & 7) << 4));
            bfr[ks][t] = *(const short8*)((const char*)Wt + byte);
        }

    #pragma unroll
    for (int nt = 0; nt < 2; ++nt){
        int nb = wv * 32 + nt * 16;
        int node = nb + lr;
        short8 af[KS];
        #pragma unroll
        for (int ks = 0; ks < KS; ++ks){
            int byte = node * RB + ((ks * 64 + lg * 16) ^ ((node & 7) << 4));
            af[ks] = *(const short8*)((const char*)As + byte);
        }
        f32x4 acc[4] = {(f32x4)0.f, (f32x4)0.f, (f32x4)0.f, (f32x4)0.f};
        #pragma unroll
        for (int ks = 0; ks < KS; ++ks)
            #pragma unroll
            for (int t = 0; t < 4; ++t)
                acc[t] = __builtin_amdgcn_mfma_f32_16x16x32_bf16(af[ks], bfr[ks][t], acc[t], 0, 0, 0);
        #pragma unroll
        for (int r = 0; r < 4; ++r){
            int n = nodeBase + nb + lg * 4 + r;
            if (n < N){
                float dv = dinv[n];
                #pragma unroll
                for (int t = 0; t < 4; ++t)
                    H8[((size_t)(unsigned)n << 6) + t * 16 + lr] = f2fp8(acc[t][r] * dv);
            }
        }
    }
}

// ---------------- fused aggregate + bias + LN + ReLU + (next matmul | pool) ----------------
// v6: 16 nodes/wave (lane: g=node l>>2, s=16B-quarter l&3), dwordx4 gathers (4 lanes
// cover one 64B row). 64 nodes/block (4 waves). Non-POOL: each wave's 16 nodes form one
// MFMA tile; y (bf16) -> per-wave swizzled LDS tile (within-wave, no barrier), W_next^T
// staged once, 8 mfma_16x16x32, write H8out with dinv folded. A-buffer eliminated.
// POOL: mean-pool reduction instead. Inactive edge slots read zeroed row N of H8in.

template<bool POOL>
__global__ __launch_bounds__(256) void agg_kernel(const unsigned char* __restrict__ H8in,
                                                  const float* __restrict__ dinv,
                                                  const int* __restrict__ col_ptr,
                                                  const int* __restrict__ col_end,
                                                  const int* __restrict__ csr_row,
                                                  const float* __restrict__ bias,
                                                  const float* __restrict__ lnw,
                                                  const float* __restrict__ lnb,
                                                  const float* __restrict__ Wn,
                                                  unsigned char* __restrict__ H8out,
                                                  float* __restrict__ pooledRep, int N){
    __shared__ int sIdx[2 * SMAX];                       // 16 KB
    __shared__ __align__(16) short ybuf[POOL ? 8 : 4096]; // 4 waves x 16x64 bf16, swizzled
    __shared__ __align__(16) short Wt[POOL ? 8 : 4096];   // W_next^T bf16, swizzled
    __shared__ float sp[POOL ? 256 : 4];
    int tid = threadIdx.x;
    int wid = tid >> 6, l = tid & 63;
    int g = l >> 2, s = l & 3;            // node sub-idx (0..15), 16B quarter (0..3)
    int nodeBase = blockIdx.x * 64;
    int n = nodeBase + wid * 16 + g;
    bool valid = (n < N);
    int nc = valid ? n : nodeBase;

    int lastN = nodeBase + 63; if (lastN > N - 1) lastN = N - 1;
    int jlo = col_ptr[nodeBase];
    int jhi = col_end[lastN];
    int cnt = jhi - jlo;

    int j0 = col_ptr[nc];
    int j1 = valid ? col_end[nc] : j0;
    int deg = j1 - j0;

    bool fast = (cnt <= SMAX);
    if (fast){
        for (int i = tid; i < cnt; i += 256) sIdx[i] = csr_row[jlo + i];
    }
    if (!POOL){
        // stage W_next^T (bf16, XOR-swizzled; same layout as matmul_kernel's Wt, RB=128)
        for (int i = tid; i < 4096; i += 256){
            int k = i >> 6, c = i & 63;
            unsigned short b = f2bfbits(Wn[i]);
            int byte = c * 128 + ((2 * k) ^ ((c & 7) << 4));
            *(short*)((char*)Wt + byte) = (short)b;
        }
    }
    __syncthreads();

    unsigned soff = (unsigned)(s << 4);   // byte offset of this lane's 16B quarter
    const char* Hb = (const char*)H8in;
    uint4 us = *(const uint4*)(Hb + ((((unsigned)nc) << 6) | soff));  // self-loop

    // wave-max degree (deg uniform within each 4-lane group)
    int mdeg = deg;
    mdeg = max(mdeg, __shfl_xor(mdeg, 4));
    mdeg = max(mdeg, __shfl_xor(mdeg, 8));
    mdeg = max(mdeg, __shfl_xor(mdeg, 16));
    mdeg = max(mdeg, __shfl_xor(mdeg, 32));

    f32x2 a0 = {0.f,0.f}, a1 = {0.f,0.f}, a2 = {0.f,0.f}, a3 = {0.f,0.f};
    f32x2 a4 = {0.f,0.f}, a5 = {0.f,0.f}, a6 = {0.f,0.f}, a7 = {0.f,0.f};

#define ACC4(u) { a0 += cvtpk<false>((u).x); a1 += cvtpk<true>((u).x); \
                  a2 += cvtpk<false>((u).y); a3 += cvtpk<true>((u).y); \
                  a4 += cvtpk<false>((u).z); a5 += cvtpk<true>((u).z); \
                  a6 += cvtpk<false>((u).w); a7 += cvtpk<true>((u).w); }
#define GLOOP(IDX) \
    for (int i = 0; i < mdeg; i += 4){ \
        int r0 = (i     < deg) ? IDX(i    ) : N; \
        int r1 = (i + 1 < deg) ? IDX(i + 1) : N; \
        int r2 = (i + 2 < deg) ? IDX(i + 2) : N; \
        int r3 = (i + 3 < deg) ? IDX(i + 3) : N; \
        uint4 u0 = *(const uint4*)(Hb + ((((unsigned)r0) << 6) | soff)); \
        uint4 u1 = *(const uint4*)(Hb + ((((unsigned)r1) << 6) | soff)); \
        uint4 u2 = *(const uint4*)(Hb + ((((unsigned)r2) << 6) | soff)); \
        uint4 u3 = *(const uint4*)(Hb + ((((unsigned)r3) << 6) | soff)); \
        ACC4(u0) ACC4(u1) ACC4(u2) ACC4(u3) \
    }

    if (fast){
        int p = j0 - jlo;
#define IDXF(e) sIdx[p + (e)]
        GLOOP(IDXF)
#undef IDXF
    } else {
#define IDXS(e) csr_row[j0 + (e)]
        GLOOP(IDXS)
#undef IDXS
    }
#undef GLOOP
#undef ACC4

    ACC_SELF: ;
    a0 += cvtpk<false>(us.x); a1 += cvtpk<true>(us.x);
    a2 += cvtpk<false>(us.y); a3 += cvtpk<true>(us.y);
    a4 += cvtpk<false>(us.z); a5 += cvtpk<true>(us.z);
    a6 += cvtpk<false>(us.w); a7 += cvtpk<true>(us.w);

    float dv = dinv[nc];
    float acc16[16] = { a0.x, a0.y, a1.x, a1.y, a2.x, a2.y, a3.x, a3.y,
                        a4.x, a4.y, a5.x, a5.y, a6.x, a6.y, a7.x, a7.y };
    float v[16], y[16];
    float4 bq[4], wq[4], cq[4];
    #pragma unroll
    for (int q = 0; q < 4; ++q){
        bq[q] = ((const float4*)bias)[(s << 2) + q];
        wq[q] = ((const float4*)lnw)[(s << 2) + q];
        cq[q] = ((const float4*)lnb)[(s << 2) + q];
    }
    #pragma unroll
    for (int j = 0; j < 16; ++j)
        v[j] = fmaf(dv, acc16[j], ((const float*)&bq[j >> 2])[j & 3]);

    float sum = 0.f;
    #pragma unroll
    for (int j = 0; j < 16; ++j) sum += v[j];
    sum += __shfl_xor(sum, 1); sum += __shfl_xor(sum, 2);
    float mu = sum * (1.0f / 64.0f);
    float var = 0.f;
    #pragma unroll
    for (int j = 0; j < 16; ++j){ float d = v[j] - mu; var = fmaf(d, d, var); }
    var += __shfl_xor(var, 1); var += __shfl_xor(var, 2);
    float rstd = rsqrtf(var * (1.0f / 64.0f) + 1e-5f);
    #pragma unroll
    for (int j = 0; j < 16; ++j){
        float d = (v[j] - mu) * rstd;
        y[j] = fmaxf(fmaf(d, ((const float*)&wq[j >> 2])[j & 3],
                             ((const float*)&cq[j >> 2])[j & 3]), 0.0f);
    }

    if (POOL){
        #pragma unroll
        for (int j = 0; j < 16; ++j){
            float z = valid ? y[j] : 0.f;
            z += __shfl_xor(z, 4); z += __shfl_xor(z, 8);
            z += __shfl_xor(z, 16); z += __shfl_xor(z, 32);
            y[j] = z;
        }
        if (l < 4){
            #pragma unroll
            for (int q = 0; q < 4; ++q)
                ((float4*)sp)[wid * 16 + (s << 2) + q] =
                    make_float4(y[4*q], y[4*q+1], y[4*q+2], y[4*q+3]);
        }
        __syncthreads();
        if (tid < 64){
            float t = sp[tid] + sp[64 + tid] + sp[128 + tid] + sp[192 + tid];
            atomicAdd(&pooledRep[(blockIdx.x & 63) * 64 + tid], t);
        }
    } else {
        // y -> per-wave swizzled LDS tile (within-wave; no barrier needed)
        char* yb = (char*)ybuf;
        int base = (wid << 11) + (g << 7);
        int sw = (g & 7) << 4;
        short8 ya, yz;
        #pragma unroll
        for (int j = 0; j < 8; ++j){ ya[j] = (short)f2bfbits(y[j]); yz[j] = (short)f2bfbits(y[8 + j]); }
        *(short8*)(yb + base + (((s << 5)     ) ^ sw)) = ya;
        *(short8*)(yb + base + (((s << 5) + 16) ^ sw)) = yz;

        int lr = l & 15, lg = l >> 4;
        short8 bfr[2][4];
        #pragma unroll
        for (int ks = 0; ks < 2; ++ks)
            #pragma unroll
            for (int t = 0; t < 4; ++t){
                int c = t * 16 + lr;
                int byte = c * 128 + ((((ks << 2) + lg) << 4) ^ ((c & 7) << 4));
                bfr[ks][t] = *(const short8*)((const char*)Wt + byte);
            }
        short8 af[2];
        #pragma unroll
        for (int ks = 0; ks < 2; ++ks){
            int byte = (wid << 11) + lr * 128 + ((((ks << 2) + lg) << 4) ^ ((lr & 7) << 4));
            af[ks] = *(const short8*)(yb + byte);
        }
        f32x4 acc[4] = {(f32x4)0.f, (f32x4)0.f, (f32x4)0.f, (f32x4)0.f};
        #pragma unroll
        for (int ks = 0; ks < 2; ++ks)
            #pragma unroll
            for (int t = 0; t < 4; ++t)
                acc[t] = __builtin_amdgcn_mfma_f32_16x16x32_bf16(af[ks], bfr[ks][t], acc[t], 0, 0, 0);
        #pragma unroll
        for (int r = 0; r < 4; ++r){
            int nn = nodeBase + (wid << 4) + (lg << 2) + r;
            if (nn < N){
                float dv2 = dinv[nn];
                #pragma unroll
                for (int t = 0; t < 4; ++t)
                    H8out[((size_t)(unsigned)nn << 6) + t * 16 + lr] = f2fp8(acc[t][r] * dv2);
            }
        }
    }
}

// ---------------- head: reduce 64 replicas + linear ----------------

__global__ __launch_bounds__(64) void final_kernel(const float* __restrict__ pooledRep,
                                                   const float* __restrict__ Wl,
                                                   const float* __restrict__ bl,
                                                   float* __restrict__ outp, float invN){
    __shared__ float pooled[64];
    int t = threadIdx.x;
    float s = 0.f;
    #pragma unroll 8
    for (int r = 0; r < 64; ++r) s += pooledRep[r * 64 + t];
    pooled[t] = s;
    __syncthreads();
    if (t < 25){
        float acc = bl[t];
        #pragma unroll 8
        for (int f = 0; f < HID; ++f)
            acc = fmaf(pooled[f] * invN, Wl[f * 25 + t], acc);
        outp[t] = acc;
    }
}

// ---------------- launch ----------------

static inline size_t alignup(size_t x){ return (x + 255) & ~(size_t)255; }

extern "C" void kernel_launch(void* const* d_in, const int* in_sizes, int n_in,
                              void* d_out, int out_size, void* d_ws, size_t ws_size,
                              hipStream_t stream) {
    const float* x   = (const float*)d_in[0];
    const int*   ei  = (const int*)d_in[1];
    const float* W1  = (const float*)d_in[2];
    const float* b1  = (const float*)d_in[3];
    const float* W2  = (const float*)d_in[4];
    const float* b2  = (const float*)d_in[5];
    const float* W3  = (const float*)d_in[6];
    const float* b3  = (const float*)d_in[7];
    const float* ln1w = (const float*)d_in[8];
    const float* ln1b = (const float*)d_in[9];
    const float* ln2w = (const float*)d_in[10];
    const float* ln2b = (const float*)d_in[11];
    const float* ln3w = (const float*)d_in[12];
    const float* ln3b = (const float*)d_in[13];
    const float* Wl  = (const float*)d_in[14];
    const float* bl  = (const float*)d_in[15];

    const int N = in_sizes[0] / 128;
    const int E = in_sizes[1] / 2;
    const int NB = (N + 127) >> BSH;
    const int* row = ei;
    const int* col = ei + E;

    char* p = (char*)d_ws;
    int*   gCur      = (int*)p;   p += alignup((size_t)NB * 4);
    float* pooledRep = (float*)p; p += alignup(64 * 64 * 4);
    size_t zeroBytes = (size_t)((char*)p - (char*)gCur);
    int*   binned    = (int*)p;   p += alignup((size_t)NB * CAP * 4);
    int*   csr_row   = (int*)p;   p += alignup((size_t)NB * CAP * 4);
    int*   col_ptr   = (int*)p;   p += alignup((size_t)N * 4);
    int*   col_end   = (int*)p;   p += alignup((size_t)N * 4);
    float* dinv      = (float*)p; p += alignup((size_t)N * 4);
    unsigned char* H8a = (unsigned char*)p; p += alignup(((size_t)N + 1) * HID);
    unsigned char* H8b = (unsigned char*)p; p += alignup(((size_t)N + 1) * HID);

    hipMemsetAsync(gCur, 0, zeroBytes, stream);

    int gB = (E + EPB - 1) / EPB;
    int gM = (N + 127) / 128;
    int gA = (N + 63) / 64;

    bin_kernel<<<gB, 1024, 0, stream>>>(row, col, E, NB, gCur, binned);
    build_kernel<<<NB, 512, 0, stream>>>(gCur, binned, csr_row, col_ptr, col_end, dinv,
                                         H8a, H8b, N);

    // layer 1 matmul
    matmul_kernel<128, float><<<gM, 256, 0, stream>>>(x, W1, dinv, H8a, N);
    // layer 1 agg + LN + ReLU + fused layer-2 matmul
    agg_kernel<false><<<gA, 256, 0, stream>>>(H8a, dinv, col_ptr, col_end, csr_row,
                                              b1, ln1w, ln1b, W2, H8b, pooledRep, N);
    // layer 2 agg + LN + ReLU + fused layer-3 matmul
    agg_kernel<false><<<gA, 256, 0, stream>>>(H8b, dinv, col_ptr, col_end, csr_row,
                                              b2, ln2w, ln2b, W3, H8a, pooledRep, N);
    // layer 3 agg + LN + ReLU + mean-pool accumulate
    agg_kernel<true><<<gA, 256, 0, stream>>>(H8a, dinv, col_ptr, col_end, csr_row,
                                             b3, ln3w, ln3b, nullptr, nullptr, pooledRep, N);

    final_kernel<<<1, 64, 0, stream>>>(pooledRep, Wl, bl, (float*)d_out, 1.0f / (float)N);
}